// Round 13
// baseline (211.852 us; speedup 1.0000x reference)
//
#include <hip/hip_runtime.h>
#include <hip/hip_bf16.h>
#include <hip/hip_fp16.h>

#define NEG 0.2f
#define L2E 1.44269504f
#define BSH 9          // 512 nodes per bucket
#define BNODES 512
#define MAXC 16384     // bucket capacity (mean ~8200, +90 sigma)
#define CHUNK 4096     // edges per k_bucket block

typedef __attribute__((ext_vector_type(8))) _Float16 half8v;
typedef __attribute__((ext_vector_type(4))) short short4v;
typedef __attribute__((ext_vector_type(4))) float f32x4;

__device__ __forceinline__ float leaky(float e) { return fmaxf(e, NEG * e); }
__device__ __forceinline__ ushort f2h(float f) {
    __half h = __float2half(f);
    return *reinterpret_cast<ushort*>(&h);
}
// p = exp2(leaky(l+adv) - e0); logits pre-scaled by log2e in GEMM epilogue
__device__ __forceinline__ float edgep(float l, float adv, float e0) {
    return __builtin_amdgcn_exp2f(leaky(l + adv) - e0);
}

// packed f16x8 row FMA: acc[c] += a * h[c]
__device__ __forceinline__ void fma8(float* acc, float a, uint4 h) {
    unsigned wv[4] = { h.x, h.y, h.z, h.w };
    #pragma unroll
    for (int j = 0; j < 4; j++) {
        __half2 hh = *reinterpret_cast<__half2*>(&wv[j]);
        float lo = __half2float(__low2half(hh));
        float hi = __half2float(__high2half(hh));
        acc[2 * j]     = fmaf(a, lo, acc[2 * j]);
        acc[2 * j + 1] = fmaf(a, hi, acc[2 * j + 1]);
    }
}

// ---------------- fused: edge bucketing (blocks [0,nbkt)) + GEMM1 (blocks [nbkt,...)) ----------------
__global__ __launch_bounds__(256) void k_bktg1(const int* __restrict__ src, const int* __restrict__ dst,
                                               int E, unsigned int* __restrict__ bbuf, int* __restrict__ bcnt,
                                               int nbkt,
                                               const float* __restrict__ x, const float* __restrict__ W,
                                               const float* __restrict__ attS, const float* __restrict__ attD,
                                               ushort* __restrict__ h1b, float* __restrict__ as1,
                                               float* __restrict__ ad1, int n) {
    __shared__ __align__(16) char smem[128 * 136 * 2];
    int tid = threadIdx.x;
    if (blockIdx.x < (unsigned)nbkt) {
        // ---- bucket role ----
        int* hcnt = (int*)smem;
        int* hoff = hcnt + 256;
        int* gbase = hoff + 256;
        int* sh = gbase + 256;
        unsigned int* lbuf = (unsigned int*)(sh + 256);
        unsigned char* map = (unsigned char*)(lbuf + CHUNK);
        hcnt[tid] = 0;
        __syncthreads();
        int e0 = blockIdx.x * CHUNK;
        unsigned int pk[16];
        int sl[16];
        unsigned char bb[16];
        #pragma unroll
        for (int r = 0; r < 16; r++) {
            int i = e0 + r * 256 + tid;
            sl[r] = -1; pk[r] = 0; bb[r] = 0;
            if (i < E) {
                int s = src[i], d = dst[i];
                int b = d >> BSH;
                pk[r] = ((unsigned int)(d & (BNODES - 1)) << 17) | (unsigned int)s;
                bb[r] = (unsigned char)b;
                sl[r] = atomicAdd(&hcnt[b], 1);
            }
        }
        __syncthreads();
        int v = hcnt[tid];
        sh[tid] = v;
        __syncthreads();
        for (int off = 1; off < 256; off <<= 1) {
            int t = (tid >= off) ? sh[tid - off] : 0;
            __syncthreads();
            sh[tid] += t;
            __syncthreads();
        }
        hoff[tid] = sh[tid] - v;  // exclusive scan
        if (v > 0) gbase[tid] = atomicAdd(&bcnt[tid], v);
        __syncthreads();
        #pragma unroll
        for (int r = 0; r < 16; r++) {
            if (sl[r] >= 0) {
                int pos = hoff[bb[r]] + sl[r];
                lbuf[pos] = pk[r];
                map[pos] = bb[r];
            }
        }
        int total = sh[255];
        __syncthreads();
        for (int j = tid; j < total; j += 256) {
            int lo = map[j];
            int p = gbase[lo] + (j - hoff[lo]);
            if (p < MAXC) bbuf[(size_t)lo * MAXC + p] = lbuf[j];
        }
    } else {
        // ---- GEMM1 role (128 rows/block, MFMA f16) ----
        ushort* Wt = (ushort*)smem;  // Wt[nn][k] = f16(W[k][nn]), ld 136
        #pragma unroll 4
        for (int it = 0; it < 64; it++) {
            int idx = tid + 256 * it;
            int k = idx >> 7, nn = idx & 127;
            Wt[nn * 136 + k] = f2h(W[idx]);
        }
        __syncthreads();
        int lane = tid & 63;
        int wid = tid >> 6;
        int l15 = lane & 15, g = lane >> 4;
        int R0 = (blockIdx.x - nbkt) * 128 + wid * 32;
        f32x4 acc[2][8];
        #pragma unroll
        for (int f = 0; f < 2; f++)
            #pragma unroll
            for (int nf = 0; nf < 8; nf++) acc[f][nf] = (f32x4){0.f, 0.f, 0.f, 0.f};
        size_t mclamp[2];
        mclamp[0] = (size_t)((R0 + l15 < n) ? R0 + l15 : n - 1);
        mclamp[1] = (size_t)((R0 + 16 + l15 < n) ? R0 + 16 + l15 : n - 1);
        #pragma unroll
        for (int ks = 0; ks < 4; ks++) {
            half8v xb[2];
            #pragma unroll
            for (int f = 0; f < 2; f++) {
                const float4* xp = (const float4*)(x + mclamp[f] * 128 + ks * 32 + g * 8);
                float4 a0 = xp[0], a1 = xp[1];
                half8v v;
                v[0] = (_Float16)a0.x; v[1] = (_Float16)a0.y; v[2] = (_Float16)a0.z; v[3] = (_Float16)a0.w;
                v[4] = (_Float16)a1.x; v[5] = (_Float16)a1.y; v[6] = (_Float16)a1.z; v[7] = (_Float16)a1.w;
                xb[f] = v;
            }
            #pragma unroll
            for (int nf = 0; nf < 8; nf++) {
                half8v wv = *(const half8v*)(&Wt[(16 * nf + l15) * 136 + ks * 32 + g * 8]);
                acc[0][nf] = __builtin_amdgcn_mfma_f32_16x16x32_f16(wv, xb[0], acc[0][nf], 0, 0, 0);
                acc[1][nf] = __builtin_amdgcn_mfma_f32_16x16x32_f16(wv, xb[1], acc[1][nf], 0, 0, 0);
            }
        }
        #pragma unroll
        for (int f = 0; f < 2; f++) {
            int m = R0 + 16 * f + l15;
            bool ok = m < n;
            float pS[4] = {0.f, 0.f, 0.f, 0.f}, pD[4] = {0.f, 0.f, 0.f, 0.f};
            #pragma unroll
            for (int nf = 0; nf < 8; nf++) {
                int n0 = 16 * nf + 4 * g;
                f32x4 a = acc[f][nf];
                if (ok) {
                    short4v s4;
                    s4[0] = (short)f2h(a[0]); s4[1] = (short)f2h(a[1]);
                    s4[2] = (short)f2h(a[2]); s4[3] = (short)f2h(a[3]);
                    *(short4v*)(h1b + (size_t)m * 128 + n0) = s4;
                }
                float4 vS = *(const float4*)(attS + n0);
                float4 vD = *(const float4*)(attD + n0);
                int hd = nf >> 1;
                pS[hd] += a[0] * vS.x + a[1] * vS.y + a[2] * vS.z + a[3] * vS.w;
                pD[hd] += a[0] * vD.x + a[1] * vD.y + a[2] * vD.z + a[3] * vD.w;
            }
            #pragma unroll
            for (int h = 0; h < 4; h++) {
                pS[h] += __shfl_xor(pS[h], 16, 64); pS[h] += __shfl_xor(pS[h], 32, 64);
                pD[h] += __shfl_xor(pD[h], 16, 64); pD[h] += __shfl_xor(pD[h], 32, 64);
            }
            if (ok && g == 0) {
                *(float4*)(as1 + (size_t)m * 4) = make_float4(pS[0] * L2E, pS[1] * L2E, pS[2] * L2E, pS[3] * L2E);
                *(float4*)(ad1 + (size_t)m * 4) = make_float4(pD[0] * L2E, pD[1] * L2E, pD[2] * L2E, pD[3] * L2E);
            }
        }
    }
}

// per bucket: self-computed base (scan of bcnt) + hist + in-LDS scan -> rs + direct scatter to csr
__global__ __launch_bounds__(256) void k_csrX(const unsigned int* __restrict__ bbuf,
                                              const int* __restrict__ bcnt,
                                              int nbuck, int n, int E,
                                              int* __restrict__ rs, int* __restrict__ csr) {
    __shared__ int hist[BNODES], off[BNODES], cur[BNODES], sh[256];
    int b = blockIdx.x, tid = threadIdx.x;
    // exclusive scan of bucket counts -> this block's segbase
    int v = (tid < nbuck) ? min(bcnt[tid], MAXC) : 0;
    sh[tid] = v;
    hist[tid] = 0; hist[tid + 256] = 0;
    cur[tid] = 0;  cur[tid + 256] = 0;
    __syncthreads();
    for (int o = 1; o < 256; o <<= 1) {
        int t = (tid >= o) ? sh[tid - o] : 0;
        __syncthreads();
        sh[tid] += t;
        __syncthreads();
    }
    int segbase = (b > 0) ? sh[b - 1] : 0;   // inclusive scan shifted = exclusive
    __syncthreads();
    int cnt = min(bcnt[b], MAXC);
    const unsigned int* p = bbuf + (size_t)b * MAXC;
    for (int i = tid; i < cnt; i += 256) atomicAdd(&hist[p[i] >> 17], 1);
    __syncthreads();
    int h0 = hist[2 * tid], h1v = hist[2 * tid + 1];
    int s = h0 + h1v;
    sh[tid] = s;
    __syncthreads();
    for (int o = 1; o < 256; o <<= 1) {
        int t = (tid >= o) ? sh[tid - o] : 0;
        __syncthreads();
        sh[tid] += t;
        __syncthreads();
    }
    int ex = sh[tid] - s;
    off[2 * tid] = ex;
    off[2 * tid + 1] = ex + h0;
    __syncthreads();
    int total = sh[255];
    int n0 = b << BSH;
    for (int l = tid; l < BNODES; l += 256) {
        int node = n0 + l;
        if (node < n) rs[node] = segbase + off[l];
    }
    if (b == gridDim.x - 1 && tid == 0) rs[n] = segbase + total;
    // direct scatter (writes land in this block's 64KB csr window; L2-resident)
    for (int i = tid; i < cnt; i += 256) {
        unsigned int e = p[i];
        int l = e >> 17;
        int s2 = atomicAdd(&cur[l], 1);
        csr[segbase + off[l] + s2] = (int)(e & 0x1FFFFu);
    }
}

// ---------------- Layer-1 fused softmax+aggregation (256-thr blocks) ----------------
// lane = 16*g + q; lane owns channels 8q..8q+7 of edges i+g (and i+4+g)
__global__ __launch_bounds__(256) void k_agg1(const int* __restrict__ rs, const int* __restrict__ csr,
                                              const ushort* __restrict__ h1b,
                                              const float* __restrict__ as1, const float* __restrict__ ad1,
                                              const float* __restrict__ b1,
                                              ushort* __restrict__ o1b, int n) {
    int w = (blockIdx.x * 256 + threadIdx.x) >> 6;
    w = __builtin_amdgcn_readfirstlane(w);
    if (w >= n) return;
    int lane = threadIdx.x & 63;
    int g = lane >> 4, q = lane & 15;
    int hd = q >> 2;
    unsigned qoff = 8u * (unsigned)q;
    float adv = ad1[(unsigned)(w * 4 + hd)];
    float e0 = leaky(as1[(unsigned)(w * 4 + hd)] + adv);
    float acc0[8], acc1[8];
    float den0 = 0.f, den1 = 0.f;
    #pragma unroll
    for (int c = 0; c < 8; c++) { acc0[c] = 0.f; acc1[c] = 0.f; }
    if (g == 0) {
        // self contribution: p = exp2(e0-e0) = 1
        uint4 hv = *(const uint4*)(h1b + (((unsigned)w << 7) + qoff));
        fma8(acc0, 1.0f, hv);
        den0 = 1.0f;
    }
    int beg = rs[w], end = rs[w + 1];
    int i = beg;
    for (; i + 8 <= end; i += 8) {
        int ea = i + g, eb = i + 4 + g;
        int sa = csr[ea], sb = csr[eb];
        float pa = edgep(as1[(unsigned)(sa * 4 + hd)], adv, e0);
        float pb = edgep(as1[(unsigned)(sb * 4 + hd)], adv, e0);
        uint4 ha = *(const uint4*)(h1b + (((unsigned)sa << 7) + qoff));
        uint4 hb = *(const uint4*)(h1b + (((unsigned)sb << 7) + qoff));
        fma8(acc0, pa, ha);
        fma8(acc1, pb, hb);
        den0 += pa; den1 += pb;
    }
    if (i < end) {
        int ea = i + g;
        int ea2 = min(ea, end - 1);
        int sa = csr[ea2];
        float pa = (ea < end) ? edgep(as1[(unsigned)(sa * 4 + hd)], adv, e0) : 0.f;
        uint4 ha = *(const uint4*)(h1b + (((unsigned)sa << 7) + qoff));
        fma8(acc0, pa, ha);
        den0 += pa;
        if (i + 4 < end) {
            int eb = i + 4 + g;
            int eb2 = min(eb, end - 1);
            int sb = csr[eb2];
            float pb = (eb < end) ? edgep(as1[(unsigned)(sb * 4 + hd)], adv, e0) : 0.f;
            uint4 hb = *(const uint4*)(h1b + (((unsigned)sb << 7) + qoff));
            fma8(acc1, pb, hb);
            den1 += pb;
        }
    }
    float den = den0 + den1;
    den += __shfl_xor(den, 16, 64);
    den += __shfl_xor(den, 32, 64);
    #pragma unroll
    for (int c = 0; c < 8; c++) {
        float v = acc0[c] + acc1[c];
        v += __shfl_xor(v, 16, 64);
        v += __shfl_xor(v, 32, 64);
        acc0[c] = v;
    }
    if (g == 0) {
        float inv = 1.0f / den;
        float4 bv0 = *(const float4*)(b1 + 8 * q);
        float4 bv1 = *(const float4*)(b1 + 8 * q + 4);
        float o[8] = { acc0[0] * inv + bv0.x, acc0[1] * inv + bv0.y,
                       acc0[2] * inv + bv0.z, acc0[3] * inv + bv0.w,
                       acc0[4] * inv + bv1.x, acc0[5] * inv + bv1.y,
                       acc0[6] * inv + bv1.z, acc0[7] * inv + bv1.w };
        ushort st[8];
        #pragma unroll
        for (int c = 0; c < 8; c++) {
            float e = (o[c] > 0.f) ? o[c] : (__expf(o[c]) - 1.f);  // ELU
            st[c] = f2h(e);
        }
        *(uint4*)(o1b + (((unsigned)w << 7) + qoff)) = *(uint4*)st;
    }
}

// ---------------- GEMM2 (128->64, MFMA f16) + logits (log2e-scaled) ----------------
__global__ __launch_bounds__(256) void k_gemm2(const ushort* __restrict__ o1b, const float* __restrict__ W,
                                               const float* __restrict__ attS, const float* __restrict__ attD,
                                               ushort* __restrict__ h2b, float* __restrict__ as2,
                                               float* __restrict__ ad2, int n) {
    __shared__ ushort Wt[64 * 136];  // Wt[n][k] = f16(W[k][n])
    int tid = threadIdx.x;
    #pragma unroll 4
    for (int it = 0; it < 32; it++) {
        int idx = tid + 256 * it;
        int k = idx >> 6, nn = idx & 63;
        Wt[nn * 136 + k] = f2h(W[idx]);
    }
    __syncthreads();
    int lane = tid & 63;
    int wid = tid >> 6;
    int l15 = lane & 15, g = lane >> 4;
    int R0 = blockIdx.x * 128 + wid * 32;
    f32x4 acc[2][4];
    #pragma unroll
    for (int f = 0; f < 2; f++)
        #pragma unroll
        for (int nf = 0; nf < 4; nf++) acc[f][nf] = (f32x4){0.f, 0.f, 0.f, 0.f};
    size_t mclamp[2];
    mclamp[0] = (size_t)((R0 + l15 < n) ? R0 + l15 : n - 1);
    mclamp[1] = (size_t)((R0 + 16 + l15 < n) ? R0 + 16 + l15 : n - 1);
    #pragma unroll
    for (int ks = 0; ks < 4; ks++) {
        half8v xb[2];
        xb[0] = *(const half8v*)(o1b + mclamp[0] * 128 + ks * 32 + g * 8);
        xb[1] = *(const half8v*)(o1b + mclamp[1] * 128 + ks * 32 + g * 8);
        #pragma unroll
        for (int nf = 0; nf < 4; nf++) {
            half8v wv = *(const half8v*)(&Wt[(16 * nf + l15) * 136 + ks * 32 + g * 8]);
            acc[0][nf] = __builtin_amdgcn_mfma_f32_16x16x32_f16(wv, xb[0], acc[0][nf], 0, 0, 0);
            acc[1][nf] = __builtin_amdgcn_mfma_f32_16x16x32_f16(wv, xb[1], acc[1][nf], 0, 0, 0);
        }
    }
    #pragma unroll
    for (int f = 0; f < 2; f++) {
        int m = R0 + 16 * f + l15;
        bool ok = m < n;
        float pS = 0.f, pD = 0.f;
        #pragma unroll
        for (int nf = 0; nf < 4; nf++) {
            int n0 = 16 * nf + 4 * g;
            f32x4 a = acc[f][nf];
            if (ok) {
                short4v s4;
                s4[0] = (short)f2h(a[0]); s4[1] = (short)f2h(a[1]);
                s4[2] = (short)f2h(a[2]); s4[3] = (short)f2h(a[3]);
                *(short4v*)(h2b + (size_t)m * 64 + n0) = s4;
            }
            float4 vS = *(const float4*)(attS + n0);
            float4 vD = *(const float4*)(attD + n0);
            pS += a[0] * vS.x + a[1] * vS.y + a[2] * vS.z + a[3] * vS.w;
            pD += a[0] * vD.x + a[1] * vD.y + a[2] * vD.z + a[3] * vD.w;
        }
        pS += __shfl_xor(pS, 16, 64); pS += __shfl_xor(pS, 32, 64);
        pD += __shfl_xor(pD, 16, 64); pD += __shfl_xor(pD, 32, 64);
        if (ok && g == 0) {
            as2[m] = pS * L2E;
            ad2[m] = pD * L2E;
        }
    }
}

// ---------------- Layer-2 fused softmax+aggregation (256-thr blocks) ----------------
// lane = 8*g + q; lane owns channels 8q..8q+7 of edges i+g (and i+8+g)
__global__ __launch_bounds__(256) void k_agg2(const int* __restrict__ rs, const int* __restrict__ csr,
                                              const ushort* __restrict__ h2b,
                                              const float* __restrict__ as2, const float* __restrict__ ad2,
                                              const float* __restrict__ b2,
                                              float* __restrict__ out, int n) {
    int w = (blockIdx.x * 256 + threadIdx.x) >> 6;
    w = __builtin_amdgcn_readfirstlane(w);
    if (w >= n) return;
    int lane = threadIdx.x & 63;
    int g = lane >> 3, q = lane & 7;
    unsigned qoff = 8u * (unsigned)q;
    float adv = ad2[w];
    float e0 = leaky(as2[w] + adv);
    float acc0[8], acc1[8];
    float den0 = 0.f, den1 = 0.f;
    #pragma unroll
    for (int c = 0; c < 8; c++) { acc0[c] = 0.f; acc1[c] = 0.f; }
    if (g == 0) {
        uint4 hv = *(const uint4*)(h2b + (((unsigned)w << 6) + qoff));
        fma8(acc0, 1.0f, hv);
        den0 = 1.0f;
    }
    int beg = rs[w], end = rs[w + 1];
    int i = beg;
    for (; i + 16 <= end; i += 16) {
        int ea = i + g, eb = i + 8 + g;
        int sa = csr[ea], sb = csr[eb];
        float pa = edgep(as2[(unsigned)sa], adv, e0);
        float pb = edgep(as2[(unsigned)sb], adv, e0);
        uint4 ha = *(const uint4*)(h2b + (((unsigned)sa << 6) + qoff));
        uint4 hb = *(const uint4*)(h2b + (((unsigned)sb << 6) + qoff));
        fma8(acc0, pa, ha);
        fma8(acc1, pb, hb);
        den0 += pa; den1 += pb;
    }
    for (; i < end; i += 8) {
        int e = i + g;
        int e2 = min(e, end - 1);
        int s = csr[e2];
        float p = (e < end) ? edgep(as2[(unsigned)s], adv, e0) : 0.f;
        uint4 hv = *(const uint4*)(h2b + (((unsigned)s << 6) + qoff));
        fma8(acc0, p, hv);
        den0 += p;
    }
    float den = den0 + den1;
    den += __shfl_xor(den, 8, 64);
    den += __shfl_xor(den, 16, 64);
    den += __shfl_xor(den, 32, 64);
    #pragma unroll
    for (int c = 0; c < 8; c++) {
        float v = acc0[c] + acc1[c];
        v += __shfl_xor(v, 8, 64);
        v += __shfl_xor(v, 16, 64);
        v += __shfl_xor(v, 32, 64);
        acc0[c] = v;
    }
    if (g == 0) {
        float inv = 1.0f / den;
        float4 bv0 = *(const float4*)(b2 + 8 * q);
        float4 bv1 = *(const float4*)(b2 + 8 * q + 4);
        float4 o0 = make_float4(acc0[0] * inv + bv0.x, acc0[1] * inv + bv0.y,
                                acc0[2] * inv + bv0.z, acc0[3] * inv + bv0.w);
        float4 o1 = make_float4(acc0[4] * inv + bv1.x, acc0[5] * inv + bv1.y,
                                acc0[6] * inv + bv1.z, acc0[7] * inv + bv1.w);
        *(float4*)(out + (size_t)w * 64 + 8 * q) = o0;
        *(float4*)(out + (size_t)w * 64 + 8 * q + 4) = o1;
    }
}

// ---------------- launcher ----------------
extern "C" void kernel_launch(void* const* d_in, const int* in_sizes, int n_in,
                              void* d_out, int out_size, void* d_ws, size_t ws_size,
                              hipStream_t stream) {
    const float* x     = (const float*)d_in[0];
    const int*   ei    = (const int*)d_in[1];
    const float* W1    = (const float*)d_in[2];
    const float* attS1 = (const float*)d_in[3];
    const float* attD1 = (const float*)d_in[4];
    const float* b1    = (const float*)d_in[5];
    const float* W2    = (const float*)d_in[6];
    const float* attS2 = (const float*)d_in[7];
    const float* attD2 = (const float*)d_in[8];
    const float* b2    = (const float*)d_in[9];
    float* out = (float*)d_out;

    int n = in_sizes[0] / 128;
    int E = in_sizes[1] / 2;
    const int* srcp = ei;
    const int* dstp = ei + E;
    int nbuck = (n + BNODES - 1) >> BSH;
    int nbkt = (E + CHUNK - 1) / CHUNK;
    int ngemm1 = (n + 127) / 128;

    char* ws = (char*)d_ws;
    size_t off = 0;
    auto A = [&](size_t bytes) -> void* {
        void* p = ws + off;
        off = (off + bytes + 255) & ~(size_t)255;
        return p;
    };
    int* rs      = (int*)A((size_t)(n + 1) * 4);
    int* bcnt    = (int*)A(1024);
    int* csr     = (int*)A((size_t)E * 4);
    float* as1   = (float*)A((size_t)n * 16);
    float* ad1   = (float*)A((size_t)n * 16);
    float* as2   = (float*)A((size_t)n * 4);
    float* ad2   = (float*)A((size_t)n * 4);
    unsigned int* bbuf = (unsigned int*)A((size_t)nbuck * MAXC * 4);  // dead after k_csrX
    ushort* h1b  = (ushort*)A((size_t)n * 128 * 2);   // h2b overlays (dead after agg1)
    ushort* o1b  = (ushort*)A((size_t)n * 128 * 2);
    ushort* h2b  = h1b;

    hipMemsetAsync(bcnt, 0, 1024, stream);
    hipLaunchKernelGGL(k_bktg1, dim3(nbkt + ngemm1), dim3(256), 0, stream,
                       srcp, dstp, E, bbuf, bcnt, nbkt, x, W1, attS1, attD1, h1b, as1, ad1, n);
    hipLaunchKernelGGL(k_csrX, dim3(nbuck), dim3(256), 0, stream, bbuf, bcnt, nbuck, n, E, rs, csr);

    hipLaunchKernelGGL(k_agg1, dim3((n * 64 + 255) / 256), dim3(256), 0, stream, rs, csr, h1b, as1, ad1, b1, o1b, n);
    hipLaunchKernelGGL(k_gemm2, dim3((n + 127) / 128), dim3(256), 0, stream, o1b, W2, attS2, attD2, h2b, as2, ad2, n);
    hipLaunchKernelGGL(k_agg2, dim3((n * 64 + 255) / 256), dim3(256), 0, stream, rs, csr, h2b, as2, ad2, b2, out, n);
}

// Round 14
// 202.967 us; speedup vs baseline: 1.0438x; 1.0438x over previous
//
#include <hip/hip_runtime.h>
#include <hip/hip_bf16.h>
#include <hip/hip_fp16.h>

#define NEG 0.2f
#define L2E 1.44269504f
#define BSH 9          // 512 nodes per bucket
#define BNODES 512
#define MAXC 16384     // bucket capacity (mean ~8200, +90 sigma)
#define CHUNK 4096     // edges per k_bucket block

typedef __attribute__((ext_vector_type(8))) _Float16 half8v;
typedef __attribute__((ext_vector_type(4))) short short4v;
typedef __attribute__((ext_vector_type(4))) float f32x4;

__device__ __forceinline__ float leaky(float e) { return fmaxf(e, NEG * e); }
__device__ __forceinline__ ushort f2h(float f) {
    __half h = __float2half(f);
    return *reinterpret_cast<ushort*>(&h);
}
// p = exp2(leaky(l+adv) - e0); logits pre-scaled by log2e in GEMM epilogue
__device__ __forceinline__ float edgep(float l, float adv, float e0) {
    return __builtin_amdgcn_exp2f(leaky(l + adv) - e0);
}

// packed f16x8 row FMA: acc[c] += a * h[c]
__device__ __forceinline__ void fma8(float* acc, float a, uint4 h) {
    unsigned wv[4] = { h.x, h.y, h.z, h.w };
    #pragma unroll
    for (int j = 0; j < 4; j++) {
        __half2 hh = *reinterpret_cast<__half2*>(&wv[j]);
        float lo = __half2float(__low2half(hh));
        float hi = __half2float(__high2half(hh));
        acc[2 * j]     = fmaf(a, lo, acc[2 * j]);
        acc[2 * j + 1] = fmaf(a, hi, acc[2 * j + 1]);
    }
}

// ---------------- fused: edge bucketing (blocks [0,nbkt)) + GEMM1 (blocks [nbkt,...)) ----------------
__global__ __launch_bounds__(256) void k_bktg1(const int* __restrict__ src, const int* __restrict__ dst,
                                               int E, unsigned int* __restrict__ bbuf, int* __restrict__ bcnt,
                                               int nbkt,
                                               const float* __restrict__ x, const float* __restrict__ W,
                                               const float* __restrict__ attS, const float* __restrict__ attD,
                                               ushort* __restrict__ h1b, float* __restrict__ as1,
                                               float* __restrict__ ad1, int n) {
    __shared__ __align__(16) char smem[128 * 136 * 2];
    int tid = threadIdx.x;
    if (blockIdx.x < (unsigned)nbkt) {
        // ---- bucket role ----
        int* hcnt = (int*)smem;
        int* hoff = hcnt + 256;
        int* gbase = hoff + 256;
        int* sh = gbase + 256;
        unsigned int* lbuf = (unsigned int*)(sh + 256);
        unsigned char* map = (unsigned char*)(lbuf + CHUNK);
        hcnt[tid] = 0;
        __syncthreads();
        int e0 = blockIdx.x * CHUNK;
        unsigned int pk[16];
        int sl[16];
        unsigned char bb[16];
        #pragma unroll
        for (int r = 0; r < 16; r++) {
            int i = e0 + r * 256 + tid;
            sl[r] = -1; pk[r] = 0; bb[r] = 0;
            if (i < E) {
                int s = src[i], d = dst[i];
                int b = d >> BSH;
                pk[r] = ((unsigned int)(d & (BNODES - 1)) << 17) | (unsigned int)s;
                bb[r] = (unsigned char)b;
                sl[r] = atomicAdd(&hcnt[b], 1);
            }
        }
        __syncthreads();
        int v = hcnt[tid];
        sh[tid] = v;
        __syncthreads();
        for (int off = 1; off < 256; off <<= 1) {
            int t = (tid >= off) ? sh[tid - off] : 0;
            __syncthreads();
            sh[tid] += t;
            __syncthreads();
        }
        hoff[tid] = sh[tid] - v;  // exclusive scan
        if (v > 0) gbase[tid] = atomicAdd(&bcnt[tid], v);
        __syncthreads();
        #pragma unroll
        for (int r = 0; r < 16; r++) {
            if (sl[r] >= 0) {
                int pos = hoff[bb[r]] + sl[r];
                lbuf[pos] = pk[r];
                map[pos] = bb[r];
            }
        }
        int total = sh[255];
        __syncthreads();
        for (int j = tid; j < total; j += 256) {
            int lo = map[j];
            int p = gbase[lo] + (j - hoff[lo]);
            if (p < MAXC) bbuf[(size_t)lo * MAXC + p] = lbuf[j];
        }
    } else {
        // ---- GEMM1 role (128 rows/block, MFMA f16) ----
        ushort* Wt = (ushort*)smem;  // Wt[nn][k] = f16(W[k][nn]), ld 136
        #pragma unroll 4
        for (int it = 0; it < 64; it++) {
            int idx = tid + 256 * it;
            int k = idx >> 7, nn = idx & 127;
            Wt[nn * 136 + k] = f2h(W[idx]);
        }
        __syncthreads();
        int lane = tid & 63;
        int wid = tid >> 6;
        int l15 = lane & 15, g = lane >> 4;
        int R0 = (blockIdx.x - nbkt) * 128 + wid * 32;
        f32x4 acc[2][8];
        #pragma unroll
        for (int f = 0; f < 2; f++)
            #pragma unroll
            for (int nf = 0; nf < 8; nf++) acc[f][nf] = (f32x4){0.f, 0.f, 0.f, 0.f};
        size_t mclamp[2];
        mclamp[0] = (size_t)((R0 + l15 < n) ? R0 + l15 : n - 1);
        mclamp[1] = (size_t)((R0 + 16 + l15 < n) ? R0 + 16 + l15 : n - 1);
        #pragma unroll
        for (int ks = 0; ks < 4; ks++) {
            half8v xb[2];
            #pragma unroll
            for (int f = 0; f < 2; f++) {
                const float4* xp = (const float4*)(x + mclamp[f] * 128 + ks * 32 + g * 8);
                float4 a0 = xp[0], a1 = xp[1];
                half8v v;
                v[0] = (_Float16)a0.x; v[1] = (_Float16)a0.y; v[2] = (_Float16)a0.z; v[3] = (_Float16)a0.w;
                v[4] = (_Float16)a1.x; v[5] = (_Float16)a1.y; v[6] = (_Float16)a1.z; v[7] = (_Float16)a1.w;
                xb[f] = v;
            }
            #pragma unroll
            for (int nf = 0; nf < 8; nf++) {
                half8v wv = *(const half8v*)(&Wt[(16 * nf + l15) * 136 + ks * 32 + g * 8]);
                acc[0][nf] = __builtin_amdgcn_mfma_f32_16x16x32_f16(wv, xb[0], acc[0][nf], 0, 0, 0);
                acc[1][nf] = __builtin_amdgcn_mfma_f32_16x16x32_f16(wv, xb[1], acc[1][nf], 0, 0, 0);
            }
        }
        #pragma unroll
        for (int f = 0; f < 2; f++) {
            int m = R0 + 16 * f + l15;
            bool ok = m < n;
            float pS[4] = {0.f, 0.f, 0.f, 0.f}, pD[4] = {0.f, 0.f, 0.f, 0.f};
            #pragma unroll
            for (int nf = 0; nf < 8; nf++) {
                int n0 = 16 * nf + 4 * g;
                f32x4 a = acc[f][nf];
                if (ok) {
                    short4v s4;
                    s4[0] = (short)f2h(a[0]); s4[1] = (short)f2h(a[1]);
                    s4[2] = (short)f2h(a[2]); s4[3] = (short)f2h(a[3]);
                    *(short4v*)(h1b + (size_t)m * 128 + n0) = s4;
                }
                float4 vS = *(const float4*)(attS + n0);
                float4 vD = *(const float4*)(attD + n0);
                int hd = nf >> 1;
                pS[hd] += a[0] * vS.x + a[1] * vS.y + a[2] * vS.z + a[3] * vS.w;
                pD[hd] += a[0] * vD.x + a[1] * vD.y + a[2] * vD.z + a[3] * vD.w;
            }
            #pragma unroll
            for (int h = 0; h < 4; h++) {
                pS[h] += __shfl_xor(pS[h], 16, 64); pS[h] += __shfl_xor(pS[h], 32, 64);
                pD[h] += __shfl_xor(pD[h], 16, 64); pD[h] += __shfl_xor(pD[h], 32, 64);
            }
            if (ok && g == 0) {
                *(float4*)(as1 + (size_t)m * 4) = make_float4(pS[0] * L2E, pS[1] * L2E, pS[2] * L2E, pS[3] * L2E);
                *(float4*)(ad1 + (size_t)m * 4) = make_float4(pD[0] * L2E, pD[1] * L2E, pD[2] * L2E, pD[3] * L2E);
            }
        }
    }
}

// per bucket: self-computed base + hist + in-LDS scan -> rs + LDS-staged coalesced csr
__global__ __launch_bounds__(256) void k_csrX(const unsigned int* __restrict__ bbuf,
                                              const int* __restrict__ bcnt,
                                              int nbuck, int n, int E,
                                              int* __restrict__ rs, int* __restrict__ csr) {
    __shared__ int hist[BNODES], off[BNODES], cur[BNODES], sh[256];
    __shared__ unsigned int obuf[MAXC];
    int b = blockIdx.x, tid = threadIdx.x;
    // exclusive scan of bucket counts -> this block's segbase
    int v = (tid < nbuck) ? min(bcnt[tid], MAXC) : 0;
    sh[tid] = v;
    hist[tid] = 0; hist[tid + 256] = 0;
    cur[tid] = 0;  cur[tid + 256] = 0;
    __syncthreads();
    for (int o = 1; o < 256; o <<= 1) {
        int t = (tid >= o) ? sh[tid - o] : 0;
        __syncthreads();
        sh[tid] += t;
        __syncthreads();
    }
    int segbase = (b > 0) ? sh[b - 1] : 0;
    __syncthreads();
    int cnt = min(bcnt[b], MAXC);
    const unsigned int* p = bbuf + (size_t)b * MAXC;
    for (int i = tid; i < cnt; i += 256) atomicAdd(&hist[p[i] >> 17], 1);
    __syncthreads();
    int h0 = hist[2 * tid], h1v = hist[2 * tid + 1];
    int s = h0 + h1v;
    sh[tid] = s;
    __syncthreads();
    for (int o = 1; o < 256; o <<= 1) {
        int t = (tid >= o) ? sh[tid - o] : 0;
        __syncthreads();
        sh[tid] += t;
        __syncthreads();
    }
    int ex = sh[tid] - s;
    off[2 * tid] = ex;
    off[2 * tid + 1] = ex + h0;
    __syncthreads();
    int total = sh[255];
    int n0 = b << BSH;
    for (int l = tid; l < BNODES; l += 256) {
        int node = n0 + l;
        if (node < n) rs[node] = segbase + off[l];
    }
    if (b == gridDim.x - 1 && tid == 0) rs[n] = segbase + total;
    for (int i = tid; i < cnt; i += 256) {
        unsigned int e = p[i];
        int l = e >> 17;
        int s2 = atomicAdd(&cur[l], 1);
        obuf[off[l] + s2] = e & 0x1FFFFu;
    }
    __syncthreads();
    for (int i = tid; i < cnt; i += 256) csr[segbase + i] = (int)obuf[i];
}

// ---------------- Layer-1 fused softmax+aggregation (grid-stride persistent waves) ----------------
// lane = 16*g + q; lane owns channels 8q..8q+7 of edges i+g (and i+4+g)
__global__ __launch_bounds__(256) void k_agg1(const int* __restrict__ rs, const int* __restrict__ csr,
                                              const ushort* __restrict__ h1b,
                                              const float* __restrict__ as1, const float* __restrict__ ad1,
                                              const float* __restrict__ b1,
                                              ushort* __restrict__ o1b, int n) {
    int nwaves = gridDim.x * 4;
    int wave0 = (blockIdx.x * 256 + threadIdx.x) >> 6;
    int lane = threadIdx.x & 63;
    int g = lane >> 4, q = lane & 15;
    int hd = q >> 2;
    unsigned qoff = 8u * (unsigned)q;
    float4 bv0 = *(const float4*)(b1 + 8 * q);
    float4 bv1 = *(const float4*)(b1 + 8 * q + 4);
    for (int w = wave0; w < n; w += nwaves) {
        float adv = ad1[(unsigned)(w * 4 + hd)];
        float e0 = leaky(as1[(unsigned)(w * 4 + hd)] + adv);
        float acc0[8], acc1[8];
        float den0 = 0.f, den1 = 0.f;
        #pragma unroll
        for (int c = 0; c < 8; c++) { acc0[c] = 0.f; acc1[c] = 0.f; }
        if (g == 0) {
            // self contribution: p = exp2(e0-e0) = 1
            uint4 hv = *(const uint4*)(h1b + (((unsigned)w << 7) + qoff));
            fma8(acc0, 1.0f, hv);
            den0 = 1.0f;
        }
        int beg = rs[w], end = rs[w + 1];
        int i = beg;
        for (; i + 8 <= end; i += 8) {
            int ea = i + g, eb = i + 4 + g;
            int sa = csr[ea], sb = csr[eb];
            float pa = edgep(as1[(unsigned)(sa * 4 + hd)], adv, e0);
            float pb = edgep(as1[(unsigned)(sb * 4 + hd)], adv, e0);
            uint4 ha = *(const uint4*)(h1b + (((unsigned)sa << 7) + qoff));
            uint4 hb = *(const uint4*)(h1b + (((unsigned)sb << 7) + qoff));
            fma8(acc0, pa, ha);
            fma8(acc1, pb, hb);
            den0 += pa; den1 += pb;
        }
        if (i < end) {
            int ea = i + g;
            int ea2 = min(ea, end - 1);
            int sa = csr[ea2];
            float pa = (ea < end) ? edgep(as1[(unsigned)(sa * 4 + hd)], adv, e0) : 0.f;
            uint4 ha = *(const uint4*)(h1b + (((unsigned)sa << 7) + qoff));
            fma8(acc0, pa, ha);
            den0 += pa;
            if (i + 4 < end) {
                int eb = i + 4 + g;
                int eb2 = min(eb, end - 1);
                int sb = csr[eb2];
                float pb = (eb < end) ? edgep(as1[(unsigned)(sb * 4 + hd)], adv, e0) : 0.f;
                uint4 hb = *(const uint4*)(h1b + (((unsigned)sb << 7) + qoff));
                fma8(acc1, pb, hb);
                den1 += pb;
            }
        }
        float den = den0 + den1;
        den += __shfl_xor(den, 16, 64);
        den += __shfl_xor(den, 32, 64);
        #pragma unroll
        for (int c = 0; c < 8; c++) {
            float v = acc0[c] + acc1[c];
            v += __shfl_xor(v, 16, 64);
            v += __shfl_xor(v, 32, 64);
            acc0[c] = v;
        }
        if (g == 0) {
            float inv = 1.0f / den;
            float o[8] = { acc0[0] * inv + bv0.x, acc0[1] * inv + bv0.y,
                           acc0[2] * inv + bv0.z, acc0[3] * inv + bv0.w,
                           acc0[4] * inv + bv1.x, acc0[5] * inv + bv1.y,
                           acc0[6] * inv + bv1.z, acc0[7] * inv + bv1.w };
            ushort st[8];
            #pragma unroll
            for (int c = 0; c < 8; c++) {
                float e = (o[c] > 0.f) ? o[c] : (__expf(o[c]) - 1.f);  // ELU
                st[c] = f2h(e);
            }
            *(uint4*)(o1b + (((unsigned)w << 7) + qoff)) = *(uint4*)st;
        }
    }
}

// ---------------- GEMM2 (128->64, MFMA f16) + logits (log2e-scaled) ----------------
__global__ __launch_bounds__(256) void k_gemm2(const ushort* __restrict__ o1b, const float* __restrict__ W,
                                               const float* __restrict__ attS, const float* __restrict__ attD,
                                               ushort* __restrict__ h2b, float* __restrict__ as2,
                                               float* __restrict__ ad2, int n) {
    __shared__ ushort Wt[64 * 136];  // Wt[n][k] = f16(W[k][n])
    int tid = threadIdx.x;
    #pragma unroll 4
    for (int it = 0; it < 32; it++) {
        int idx = tid + 256 * it;
        int k = idx >> 6, nn = idx & 63;
        Wt[nn * 136 + k] = f2h(W[idx]);
    }
    __syncthreads();
    int lane = tid & 63;
    int wid = tid >> 6;
    int l15 = lane & 15, g = lane >> 4;
    int R0 = blockIdx.x * 128 + wid * 32;
    f32x4 acc[2][4];
    #pragma unroll
    for (int f = 0; f < 2; f++)
        #pragma unroll
        for (int nf = 0; nf < 4; nf++) acc[f][nf] = (f32x4){0.f, 0.f, 0.f, 0.f};
    size_t mclamp[2];
    mclamp[0] = (size_t)((R0 + l15 < n) ? R0 + l15 : n - 1);
    mclamp[1] = (size_t)((R0 + 16 + l15 < n) ? R0 + 16 + l15 : n - 1);
    #pragma unroll
    for (int ks = 0; ks < 4; ks++) {
        half8v xb[2];
        xb[0] = *(const half8v*)(o1b + mclamp[0] * 128 + ks * 32 + g * 8);
        xb[1] = *(const half8v*)(o1b + mclamp[1] * 128 + ks * 32 + g * 8);
        #pragma unroll
        for (int nf = 0; nf < 4; nf++) {
            half8v wv = *(const half8v*)(&Wt[(16 * nf + l15) * 136 + ks * 32 + g * 8]);
            acc[0][nf] = __builtin_amdgcn_mfma_f32_16x16x32_f16(wv, xb[0], acc[0][nf], 0, 0, 0);
            acc[1][nf] = __builtin_amdgcn_mfma_f32_16x16x32_f16(wv, xb[1], acc[1][nf], 0, 0, 0);
        }
    }
    #pragma unroll
    for (int f = 0; f < 2; f++) {
        int m = R0 + 16 * f + l15;
        bool ok = m < n;
        float pS = 0.f, pD = 0.f;
        #pragma unroll
        for (int nf = 0; nf < 4; nf++) {
            int n0 = 16 * nf + 4 * g;
            f32x4 a = acc[f][nf];
            if (ok) {
                short4v s4;
                s4[0] = (short)f2h(a[0]); s4[1] = (short)f2h(a[1]);
                s4[2] = (short)f2h(a[2]); s4[3] = (short)f2h(a[3]);
                *(short4v*)(h2b + (size_t)m * 64 + n0) = s4;
            }
            float4 vS = *(const float4*)(attS + n0);
            float4 vD = *(const float4*)(attD + n0);
            pS += a[0] * vS.x + a[1] * vS.y + a[2] * vS.z + a[3] * vS.w;
            pD += a[0] * vD.x + a[1] * vD.y + a[2] * vD.z + a[3] * vD.w;
        }
        pS += __shfl_xor(pS, 16, 64); pS += __shfl_xor(pS, 32, 64);
        pD += __shfl_xor(pD, 16, 64); pD += __shfl_xor(pD, 32, 64);
        if (ok && g == 0) {
            as2[m] = pS * L2E;
            ad2[m] = pD * L2E;
        }
    }
}

// ---------------- Layer-2 fused softmax+aggregation (grid-stride persistent waves) ----------------
// lane = 8*g + q; lane owns channels 8q..8q+7 of edges i+g (and i+8+g)
__global__ __launch_bounds__(256) void k_agg2(const int* __restrict__ rs, const int* __restrict__ csr,
                                              const ushort* __restrict__ h2b,
                                              const float* __restrict__ as2, const float* __restrict__ ad2,
                                              const float* __restrict__ b2,
                                              float* __restrict__ out, int n) {
    int nwaves = gridDim.x * 4;
    int wave0 = (blockIdx.x * 256 + threadIdx.x) >> 6;
    int lane = threadIdx.x & 63;
    int g = lane >> 3, q = lane & 7;
    unsigned qoff = 8u * (unsigned)q;
    float4 bv0 = *(const float4*)(b2 + 8 * q);
    float4 bv1 = *(const float4*)(b2 + 8 * q + 4);
    for (int w = wave0; w < n; w += nwaves) {
        float adv = ad2[w];
        float e0 = leaky(as2[w] + adv);
        float acc0[8], acc1[8];
        float den0 = 0.f, den1 = 0.f;
        #pragma unroll
        for (int c = 0; c < 8; c++) { acc0[c] = 0.f; acc1[c] = 0.f; }
        if (g == 0) {
            uint4 hv = *(const uint4*)(h2b + (((unsigned)w << 6) + qoff));
            fma8(acc0, 1.0f, hv);
            den0 = 1.0f;
        }
        int beg = rs[w], end = rs[w + 1];
        int i = beg;
        for (; i + 16 <= end; i += 16) {
            int ea = i + g, eb = i + 8 + g;
            int sa = csr[ea], sb = csr[eb];
            float pa = edgep(as2[(unsigned)sa], adv, e0);
            float pb = edgep(as2[(unsigned)sb], adv, e0);
            uint4 ha = *(const uint4*)(h2b + (((unsigned)sa << 6) + qoff));
            uint4 hb = *(const uint4*)(h2b + (((unsigned)sb << 6) + qoff));
            fma8(acc0, pa, ha);
            fma8(acc1, pb, hb);
            den0 += pa; den1 += pb;
        }
        for (; i < end; i += 8) {
            int e = i + g;
            int e2 = min(e, end - 1);
            int s = csr[e2];
            float p = (e < end) ? edgep(as2[(unsigned)s], adv, e0) : 0.f;
            uint4 hv = *(const uint4*)(h2b + (((unsigned)s << 6) + qoff));
            fma8(acc0, p, hv);
            den0 += p;
        }
        float den = den0 + den1;
        den += __shfl_xor(den, 8, 64);
        den += __shfl_xor(den, 16, 64);
        den += __shfl_xor(den, 32, 64);
        #pragma unroll
        for (int c = 0; c < 8; c++) {
            float v = acc0[c] + acc1[c];
            v += __shfl_xor(v, 8, 64);
            v += __shfl_xor(v, 16, 64);
            v += __shfl_xor(v, 32, 64);
            acc0[c] = v;
        }
        if (g == 0) {
            float inv = 1.0f / den;
            float4 o0 = make_float4(acc0[0] * inv + bv0.x, acc0[1] * inv + bv0.y,
                                    acc0[2] * inv + bv0.z, acc0[3] * inv + bv0.w);
            float4 o1 = make_float4(acc0[4] * inv + bv1.x, acc0[5] * inv + bv1.y,
                                    acc0[6] * inv + bv1.z, acc0[7] * inv + bv1.w);
            *(float4*)(out + (size_t)w * 64 + 8 * q) = o0;
            *(float4*)(out + (size_t)w * 64 + 8 * q + 4) = o1;
        }
    }
}

// ---------------- launcher ----------------
extern "C" void kernel_launch(void* const* d_in, const int* in_sizes, int n_in,
                              void* d_out, int out_size, void* d_ws, size_t ws_size,
                              hipStream_t stream) {
    const float* x     = (const float*)d_in[0];
    const int*   ei    = (const int*)d_in[1];
    const float* W1    = (const float*)d_in[2];
    const float* attS1 = (const float*)d_in[3];
    const float* attD1 = (const float*)d_in[4];
    const float* b1    = (const float*)d_in[5];
    const float* W2    = (const float*)d_in[6];
    const float* attS2 = (const float*)d_in[7];
    const float* attD2 = (const float*)d_in[8];
    const float* b2    = (const float*)d_in[9];
    float* out = (float*)d_out;

    int n = in_sizes[0] / 128;
    int E = in_sizes[1] / 2;
    const int* srcp = ei;
    const int* dstp = ei + E;
    int nbuck = (n + BNODES - 1) >> BSH;
    int nbkt = (E + CHUNK - 1) / CHUNK;
    int ngemm1 = (n + 127) / 128;

    char* ws = (char*)d_ws;
    size_t off = 0;
    auto A = [&](size_t bytes) -> void* {
        void* p = ws + off;
        off = (off + bytes + 255) & ~(size_t)255;
        return p;
    };
    int* rs      = (int*)A((size_t)(n + 1) * 4);
    int* bcnt    = (int*)A(1024);
    int* csr     = (int*)A((size_t)E * 4);
    float* as1   = (float*)A((size_t)n * 16);
    float* ad1   = (float*)A((size_t)n * 16);
    float* as2   = (float*)A((size_t)n * 4);
    float* ad2   = (float*)A((size_t)n * 4);
    unsigned int* bbuf = (unsigned int*)A((size_t)nbuck * MAXC * 4);  // dead after k_csrX
    ushort* h1b  = (ushort*)A((size_t)n * 128 * 2);   // h2b overlays (dead after agg1)
    ushort* o1b  = (ushort*)A((size_t)n * 128 * 2);
    ushort* h2b  = h1b;

    hipMemsetAsync(bcnt, 0, 1024, stream);
    hipLaunchKernelGGL(k_bktg1, dim3(nbkt + ngemm1), dim3(256), 0, stream,
                       srcp, dstp, E, bbuf, bcnt, nbkt, x, W1, attS1, attD1, h1b, as1, ad1, n);
    hipLaunchKernelGGL(k_csrX, dim3(nbuck), dim3(256), 0, stream, bbuf, bcnt, nbuck, n, E, rs, csr);

    hipLaunchKernelGGL(k_agg1, dim3(2048), dim3(256), 0, stream, rs, csr, h1b, as1, ad1, b1, o1b, n);
    hipLaunchKernelGGL(k_gemm2, dim3((n + 127) / 128), dim3(256), 0, stream, o1b, W2, attS2, attD2, h2b, as2, ad2, n);
    hipLaunchKernelGGL(k_agg2, dim3(2048), dim3(256), 0, stream, rs, csr, h2b, as2, ad2, b2, out, n);
}